// Round 14
// baseline (2812.547 us; speedup 1.0000x reference)
//
#include <hip/hip_runtime.h>
#include <hip/hip_cooperative_groups.h>
#include <math.h>

namespace cg = cooperative_groups;

#define NN 100000
#define NN2 100032               // padded to 64 rows
#define NE 640000
#define H 128
#define AD 25
#define ED 10
#define RD 64
#define NL 4
#define NB_E (NE / 64 + 1)       // 10001 edge blocks
#define NSB ((NN + 255) / 256)   // 391 scan blocks
#define CAP 256

typedef short bfrag __attribute__((ext_vector_type(8)));
typedef float floatx4 __attribute__((ext_vector_type(4)));
typedef unsigned short ushort;

#define MFMA(a, b, c) __builtin_amdgcn_mfma_f32_16x16x32_bf16(a, b, c, 0, 0, 0)

__device__ __forceinline__ ushort f2bf(float f) {
    unsigned u = __float_as_uint(f);
    unsigned r = (u + 0x7FFFu + ((u >> 16) & 1u)) >> 16;
    return (ushort)r;
}
__device__ __forceinline__ float bf2f(ushort b) {
    return __uint_as_float(((unsigned)b) << 16);
}
__device__ __forceinline__ float gelu_t(float x) {
    float u = 0.7978845608028654f * (x + 0.044715f * x * x * x);
    float e = __expf(2.0f * u);
    float th = 1.0f - 2.0f / (e + 1.0f);
    return 0.5f * x * (1.0f + th);
}
__device__ __forceinline__ float sigm(float x) {
    return 1.0f / (1.0f + __expf(-x));
}

// ---- ONE cooperative kernel: init + hist + scan + scatter + blockrange + cvtperm ----
__global__ void k_prep(const int* __restrict__ ei, const float* __restrict__ ea,
                       int* __restrict__ hist, int* __restrict__ incl,
                       int* __restrict__ bsum, int* __restrict__ row_ptr,
                       int* __restrict__ cursor, int* __restrict__ perm,
                       int* __restrict__ nf, int* __restrict__ nl,
                       ushort* __restrict__ eapbf, ushort* __restrict__ aggbf) {
    cg::grid_group grid = cg::this_grid();
    __shared__ int s[512];
    const int tid = threadIdx.x;
    const int gtid = blockIdx.x * 256 + tid;
    const int gsz = gridDim.x * 256;

    // A: init hist, nf/nl, zero aggbf
    for (int i = gtid; i < NN; i += gsz) hist[i] = 0;
    for (int i = gtid; i < NB_E; i += gsz) { nf[i] = 0x7fffffff; nl[i] = -1; }
    uint4 z; z.x = z.y = z.z = z.w = 0u;
    for (int i = gtid; i < NN2 * 16; i += gsz) ((uint4*)aggbf)[i] = z;
    grid.sync();

    // B: histogram of dst
    for (int e = gtid; e < NE; e += gsz) atomicAdd(&hist[ei[NE + e]], 1);
    grid.sync();

    // C1: per-256-chunk inclusive scan (blocks 0..NSB-1)
    if (blockIdx.x < NSB) {
        int i = blockIdx.x * 256 + tid;
        s[tid] = (i < NN) ? hist[i] : 0;
        __syncthreads();
        for (int off = 1; off < 256; off <<= 1) {
            int t = (tid >= off) ? s[tid - off] : 0;
            __syncthreads();
            s[tid] += t;
            __syncthreads();
        }
        if (i < NN) incl[i] = s[tid];
        if (tid == 255) bsum[blockIdx.x] = s[255];
    }
    grid.sync();

    // C2: block 0 scans the NSB block sums (512-wide HS, 2 elems/thread)
    if (blockIdx.x == 0) {
        s[tid] = (tid < NSB) ? bsum[tid] : 0;
        s[tid + 256] = (tid + 256 < NSB) ? bsum[tid + 256] : 0;
        __syncthreads();
        for (int off = 1; off < 512; off <<= 1) {
            int v0 = (tid >= off) ? s[tid - off] : 0;
            int v1 = (tid + 256 >= off) ? s[tid + 256 - off] : 0;
            __syncthreads();
            s[tid] += v0;
            s[tid + 256] += v1;
            __syncthreads();
        }
        if (tid < NSB) bsum[tid] = (tid > 0) ? s[tid - 1] : 0;
        if (tid + 256 < NSB) bsum[tid + 256] = s[tid + 255];
    }
    grid.sync();

    // C3: row_ptr (exclusive) + cursor copy
    for (int i = gtid; i < NN; i += gsz) {
        int rp = bsum[i >> 8] + incl[i] - hist[i];
        row_ptr[i] = rp;
        cursor[i] = rp;
    }
    if (gtid == 0) row_ptr[NN] = NE;
    grid.sync();

    // D: scatter edge ids into perm (sorted by dst)
    for (int e = gtid; e < NE; e += gsz) {
        int d = ei[NE + e];
        int pos = atomicAdd(&cursor[d], 1);
        perm[pos] = e;
    }
    grid.sync();

    // E: blockrange + permuted edge-attr convert (independent outputs)
    for (int n = gtid; n < NN; n += gsz) {
        int b = row_ptr[n] >> 6;
        atomicMin(&nf[b], n);
        atomicMax(&nl[b], n);
    }
    for (int j = gtid; j < NE; j += gsz) {
        const float* src = ea + (size_t)perm[j] * ED;
        unsigned u[8];
#pragma unroll
        for (int k = 0; k < 5; ++k)
            u[k] = (unsigned)f2bf(src[2 * k]) | ((unsigned)f2bf(src[2 * k + 1]) << 16);
        u[5] = u[6] = u[7] = 0u;
        uint4* o = (uint4*)(eapbf + (size_t)j * 16);
        uint4 a; a.x = u[0]; a.y = u[1]; a.z = u[2]; a.w = u[3];
        uint4 b; b.x = u[4]; b.y = u[5]; b.z = u[6]; b.w = u[7];
        o[0] = a; o[1] = b;
    }
}

// ---------------- ALL weight transposes + x convert in ONE launch ----------------
__global__ void k_wtall(ushort* __restrict__ wt, ushort* __restrict__ xbf,
                        const float* __restrict__ x,
                        const float* __restrict__ s0, const float* __restrict__ s1,
                        const float* __restrict__ s2, const float* __restrict__ s3,
                        const float* __restrict__ s4, const float* __restrict__ s5,
                        const float* __restrict__ s6, const float* __restrict__ s7,
                        const float* __restrict__ s8, const float* __restrict__ s9) {
    int idx = blockIdx.x * 256 + threadIdx.x;
    if (idx >= 389120) {
        // xbf segment: [NN2][32] <- x[NN][25]
        int lidx = idx - 389120;
        if (lidx >= NN2 * 32) return;
        int r = lidx >> 5, k = lidx & 31;
        xbf[lidx] = (r < NN && k < 25) ? f2bf(x[(size_t)r * 25 + k]) : 0;
        return;
    }
    const float* src;
    int Ks, N, Kd, off;
    if (idx < 4096)        { src = s0; Ks = 25;  N = 128; Kd = 32;  off = 0; }
    else if (idx < 20480)  { src = s1; Ks = 128; N = 128; Kd = 128; off = 4096; }
    else if (idx < 36864)  { src = s2; Ks = 10;  N = 128; Kd = 32;  off = 20480; }
    else if (idx < 102400) { src = s3; Ks = 128; N = 128; Kd = 128; off = 36864; }
    else if (idx < 167936) { src = s4; Ks = 128; N = 128; Kd = 128; off = 102400; }
    else if (idx < 233472) { src = s5; Ks = 128; N = 128; Kd = 128; off = 167936; }
    else if (idx < 364544) { src = s6; Ks = 256; N = 128; Kd = 256; off = 233472; }
    else if (idx < 372736) { src = s7; Ks = 128; N = 64;  Kd = 128; off = 364544; }
    else if (idx < 380928) { src = s8; Ks = 128; N = 64;  Kd = 128; off = 372736; }
    else                   { src = s9; Ks = 128; N = 64;  Kd = 128; off = 380928; }
    int lidx = idx - off;
    int nk = N * Kd;
    int b = lidx / nk;
    int rem = lidx - b * nk;
    int n = rem / Kd, k = rem - n * Kd;
    float v = (k < Ks) ? src[((size_t)b * Ks + k) * N + n] : 0.0f;
    wt[idx] = f2bf(v);
}

// ---- FUSED encoder MLP2 + layer-0 msg MLP2 (wave-local sH reuse, swapped G2) ----
__global__ void __launch_bounds__(256)
k_encmsg(const ushort* __restrict__ xbf, ushort* __restrict__ hbf,
         ushort* __restrict__ mbf,
         const ushort* __restrict__ EW1t, const float* __restrict__ EB1,
         const ushort* __restrict__ EW2t, const float* __restrict__ EB2,
         const ushort* __restrict__ MW1t, const float* __restrict__ MB1,
         const ushort* __restrict__ MW2t, const float* __restrict__ MB2) {
    __shared__ ushort sH[64 * 136];
    const int tid = threadIdx.x;
    const int w = tid >> 6, lane = tid & 63, lr = lane & 15, lg = lane >> 4;
    const int rowB = blockIdx.x * 64 + w * 16 + lr;
    ushort* sHrow = sH + (w * 16 + lr) * 136;

    bfrag bv0 = *(const bfrag*)(xbf + (size_t)rowB * 32 + lg * 8);
    floatx4 acc[8];
#pragma unroll
    for (int t = 0; t < 8; ++t) acc[t] = (floatx4){0.f, 0.f, 0.f, 0.f};
#pragma unroll
    for (int t = 0; t < 8; ++t) {
        bfrag av = *(const bfrag*)(EW1t + (t * 16 + lr) * 32 + lg * 8);
        acc[t] = MFMA(av, bv0, acc[t]);
    }
#pragma unroll
    for (int t = 0; t < 8; ++t) {
        const float4 b1 = *(const float4*)(EB1 + t * 16 + lg * 4);
        float h0 = gelu_t(acc[t][0] + b1.x), h1 = gelu_t(acc[t][1] + b1.y);
        float h2 = gelu_t(acc[t][2] + b1.z), h3 = gelu_t(acc[t][3] + b1.w);
        uint2 p;
        p.x = (unsigned)f2bf(h0) | ((unsigned)f2bf(h1) << 16);
        p.y = (unsigned)f2bf(h2) | ((unsigned)f2bf(h3) << 16);
        *(uint2*)(sHrow + t * 16 + lg * 4) = p;
    }
#pragma unroll
    for (int t = 0; t < 8; ++t) acc[t] = (floatx4){0.f, 0.f, 0.f, 0.f};
#pragma unroll
    for (int kb = 0; kb < 4; ++kb) {
        bfrag av = *(const bfrag*)(sHrow + kb * 32 + lg * 8);
#pragma unroll
        for (int t = 0; t < 8; ++t) {
            bfrag bw = *(const bfrag*)(EW2t + (t * 16 + lr) * 128 + kb * 32 + lg * 8);
            acc[t] = MFMA(bw, av, acc[t]);
        }
    }
#pragma unroll
    for (int t = 0; t < 8; ++t) {
        const float4 b2 = *(const float4*)(EB2 + t * 16 + lg * 4);
        uint2 p;
        p.x = (unsigned)f2bf(acc[t][0] + b2.x) |
              ((unsigned)f2bf(acc[t][1] + b2.y) << 16);
        p.y = (unsigned)f2bf(acc[t][2] + b2.z) |
              ((unsigned)f2bf(acc[t][3] + b2.w) << 16);
        if (rowB < NN) *(uint2*)(hbf + (size_t)rowB * 128 + t * 16 + lg * 4) = p;
        *(uint2*)(sHrow + t * 16 + lg * 4) = p;
    }
#pragma unroll
    for (int t = 0; t < 8; ++t) acc[t] = (floatx4){0.f, 0.f, 0.f, 0.f};
#pragma unroll
    for (int kb = 0; kb < 4; ++kb) {
        bfrag bv = *(const bfrag*)(sHrow + kb * 32 + lg * 8);
#pragma unroll
        for (int t = 0; t < 8; ++t) {
            bfrag av = *(const bfrag*)(MW1t + (t * 16 + lr) * 128 + kb * 32 + lg * 8);
            acc[t] = MFMA(av, bv, acc[t]);
        }
    }
#pragma unroll
    for (int t = 0; t < 8; ++t) {
        const float4 b1 = *(const float4*)(MB1 + t * 16 + lg * 4);
        float h0 = gelu_t(acc[t][0] + b1.x), h1 = gelu_t(acc[t][1] + b1.y);
        float h2 = gelu_t(acc[t][2] + b1.z), h3 = gelu_t(acc[t][3] + b1.w);
        uint2 p;
        p.x = (unsigned)f2bf(h0) | ((unsigned)f2bf(h1) << 16);
        p.y = (unsigned)f2bf(h2) | ((unsigned)f2bf(h3) << 16);
        *(uint2*)(sHrow + t * 16 + lg * 4) = p;
    }
#pragma unroll
    for (int t = 0; t < 8; ++t) acc[t] = (floatx4){0.f, 0.f, 0.f, 0.f};
#pragma unroll
    for (int kb = 0; kb < 4; ++kb) {
        bfrag av = *(const bfrag*)(sHrow + kb * 32 + lg * 8);
#pragma unroll
        for (int t = 0; t < 8; ++t) {
            bfrag bw = *(const bfrag*)(MW2t + (t * 16 + lr) * 128 + kb * 32 + lg * 8);
            acc[t] = MFMA(bw, av, acc[t]);
        }
    }
    if (rowB < NN) {
        ushort* orow = mbf + (size_t)rowB * 128;
#pragma unroll
        for (int t = 0; t < 8; ++t) {
            const float4 b2 = *(const float4*)(MB2 + t * 16 + lg * 4);
            uint2 p;
            p.x = (unsigned)f2bf(acc[t][0] + b2.x) |
                  ((unsigned)f2bf(acc[t][1] + b2.y) << 16);
            p.y = (unsigned)f2bf(acc[t][2] + b2.z) |
                  ((unsigned)f2bf(acc[t][3] + b2.w) << 16);
            *(uint2*)(orow + t * 16 + lg * 4) = p;
        }
    }
}

// ------ A: edge-weight GEMM (proven staged version, swapped G2) ----
__global__ void __launch_bounds__(256)
k_ew(const ushort* __restrict__ eap, ushort* __restrict__ ewp, int S,
     const ushort* __restrict__ W1t, const float* __restrict__ B1,
     const ushort* __restrict__ W2t, const float* __restrict__ B2) {
    __shared__ ushort sea[128 * 40];
    __shared__ ushort sH[4][16 * 136];
    const int tid = threadIdx.x;
    const int w = tid >> 6, lane = tid & 63, lr = lane & 15, lg = lane >> 4;
    const int jl0 = blockIdx.x * 128;

    {
        int r = tid >> 1, half = tid & 1;
        int j = S + jl0 + r;
        uint4 z; z.x = z.y = z.z = z.w = 0u;
        uint4 v = z;
        if (j < NE) v = *(const uint4*)(eap + (size_t)j * 16 + half * 8);
        *(uint4*)(sea + r * 40 + half * 8) = v;
        *(uint4*)(sea + r * 40 + 16 + half * 8) = z;
    }
    bfrag av1[8];
#pragma unroll
    for (int t = 0; t < 8; ++t)
        av1[t] = *(const bfrag*)(W1t + (t * 16 + lr) * 32 + lg * 8);
    __syncthreads();

    for (int rt = 0; rt < 2; ++rt) {
        const int row_l = w * 32 + rt * 16;
        floatx4 acc[8];
#pragma unroll
        for (int t = 0; t < 8; ++t) acc[t] = (floatx4){0.f, 0.f, 0.f, 0.f};
        bfrag bv = *(const bfrag*)(sea + (row_l + lr) * 40 + lg * 8);
#pragma unroll
        for (int t = 0; t < 8; ++t) acc[t] = MFMA(av1[t], bv, acc[t]);
        ushort* sHr = sH[w] + lr * 136;
#pragma unroll
        for (int t = 0; t < 8; ++t) {
            const float4 b1 = *(const float4*)(B1 + t * 16 + lg * 4);
            float h0 = gelu_t(acc[t][0] + b1.x), h1 = gelu_t(acc[t][1] + b1.y);
            float h2 = gelu_t(acc[t][2] + b1.z), h3 = gelu_t(acc[t][3] + b1.w);
            uint2 p;
            p.x = (unsigned)f2bf(h0) | ((unsigned)f2bf(h1) << 16);
            p.y = (unsigned)f2bf(h2) | ((unsigned)f2bf(h3) << 16);
            *(uint2*)(sHr + t * 16 + lg * 4) = p;
        }
#pragma unroll
        for (int t = 0; t < 8; ++t) acc[t] = (floatx4){0.f, 0.f, 0.f, 0.f};
#pragma unroll
        for (int kb = 0; kb < 4; ++kb) {
            bfrag av = *(const bfrag*)(sH[w] + lr * 136 + kb * 32 + lg * 8);
#pragma unroll
            for (int t = 0; t < 8; ++t) {
                bfrag bw = *(const bfrag*)(W2t + (t * 16 + lr) * 128 + kb * 32 + lg * 8);
                acc[t] = MFMA(bw, av, acc[t]);
            }
        }
        const int jl = jl0 + row_l + lr;
        if (S + jl < NE) {
            ushort* orow = ewp + (size_t)jl * 128;
#pragma unroll
            for (int t = 0; t < 8; ++t) {
                const float4 b2 = *(const float4*)(B2 + t * 16 + lg * 4);
                uint2 p;
                p.x = (unsigned)f2bf(acc[t][0] + b2.x) |
                      ((unsigned)f2bf(acc[t][1] + b2.y) << 16);
                p.y = (unsigned)f2bf(acc[t][2] + b2.z) |
                      ((unsigned)f2bf(acc[t][3] + b2.w) << 16);
                *(uint2*)(orow + t * 16 + lg * 4) = p;
            }
        }
    }
}

// ---------------- B: gather-multiply-segment-mean (2-deep prefetch) ----------
__global__ void __launch_bounds__(256)
k_gms(const int* __restrict__ ei, const int* __restrict__ perm,
      const int* __restrict__ row_ptr, const int* __restrict__ nf,
      const int* __restrict__ nl, const ushort* __restrict__ ewp, int S,
      const ushort* __restrict__ mbf, ushort* __restrict__ aggbf) {
    __shared__ int ssrc[CAP], sdst[CAP], sseg[CAP];
    __shared__ int snode[64];
    __shared__ float sinvd[64];
    __shared__ float sagg[64 * 132];
    __shared__ int swtot[4];
    __shared__ int s_nseg;

    const int b = blockIdx.x;
    const int n0 = nf[b];
    if (n0 >= NN) return;
    const int n1 = nl[b];
    const int e0 = row_ptr[n0];
    int ne = row_ptr[n1 + 1] - e0;
    if (ne <= 0) return;
    const int ncl = (ne < CAP) ? ne : CAP;

    const int tid = threadIdx.x;
    const int w = tid >> 6, lane = tid & 63;

    for (int i = tid; i < 64 * 132; i += 256) sagg[i] = 0.0f;

    int dstv = -1 - tid;
    if (tid < ncl) {
        int e = perm[e0 + tid];
        ssrc[tid] = ei[e];
        dstv = ei[NE + e];
    }
    sdst[tid] = dstv;
    __syncthreads();

    int f = 0;
    if (tid < ncl) f = (tid == 0) ? 1 : (sdst[tid] != sdst[tid - 1]);
    unsigned long long mk = __ballot(f);
    int incl = __popcll(mk & (~0ull >> (63 - lane)));
    if (lane == 63) swtot[w] = incl;
    __syncthreads();
    int woff = 0;
    for (int i = 0; i < w; ++i) woff += swtot[i];
    int segid = woff + incl;
    sseg[tid] = segid - 1;
    if (f) {
        int s = segid - 1;
        snode[s] = dstv;
        sinvd[s] = 1.0f / (float)(row_ptr[dstv + 1] - row_ptr[dstv]);
    }
    if (tid == 255) s_nseg = segid;
    __syncthreads();
    const int nseg = s_nseg;

    const int c0 = (tid & 31) * 4;
    const int g = tid >> 5;
    const int chunk = (ncl + 7) >> 3;
    const int j0 = g * chunk;
    const int j1 = (j0 + chunk < ncl) ? (j0 + chunk) : ncl;
    const int be = e0 - S;
    int cs = -1;
    float v0 = 0.f, v1 = 0.f, v2 = 0.f, v3 = 0.f;
    uint2 ewc, mvc;
    if (j0 < j1) {
        ewc = *(const uint2*)(ewp + (size_t)(be + j0) * 128 + c0);
        mvc = *(const uint2*)(mbf + (size_t)ssrc[j0] * 128 + c0);
    }
    for (int j = j0; j < j1; ++j) {
        uint2 ewn = ewc, mvn = mvc;
        if (j + 1 < j1) {
            ewn = *(const uint2*)(ewp + (size_t)(be + j + 1) * 128 + c0);
            mvn = *(const uint2*)(mbf + (size_t)ssrc[j + 1] * 128 + c0);
        }
        float a0 = bf2f((ushort)(ewc.x & 0xFFFF)) * bf2f((ushort)(mvc.x & 0xFFFF));
        float a1 = bf2f((ushort)(ewc.x >> 16)) * bf2f((ushort)(mvc.x >> 16));
        float a2 = bf2f((ushort)(ewc.y & 0xFFFF)) * bf2f((ushort)(mvc.y & 0xFFFF));
        float a3 = bf2f((ushort)(ewc.y >> 16)) * bf2f((ushort)(mvc.y >> 16));
        int sg = sseg[j];
        if (sg != cs) {
            if (cs >= 0) {
                float* p = &sagg[cs * 132 + c0];
                atomicAdd(p + 0, v0); atomicAdd(p + 1, v1);
                atomicAdd(p + 2, v2); atomicAdd(p + 3, v3);
            }
            cs = sg; v0 = a0; v1 = a1; v2 = a2; v3 = a3;
        } else {
            v0 += a0; v1 += a1; v2 += a2; v3 += a3;
        }
        ewc = ewn; mvc = mvn;
    }
    if (cs >= 0) {
        float* p = &sagg[cs * 132 + c0];
        atomicAdd(p + 0, v0); atomicAdd(p + 1, v1);
        atomicAdd(p + 2, v2); atomicAdd(p + 3, v3);
    }
    __syncthreads();
    for (int i = tid; i < nseg * 32; i += 256) {
        int s = i >> 5, qd = i & 31;
        float inv = sinvd[s];
        const float* p = &sagg[s * 132 + qd * 4];
        uint2 pk;
        pk.x = (unsigned)f2bf(p[0] * inv) | ((unsigned)f2bf(p[1] * inv) << 16);
        pk.y = (unsigned)f2bf(p[2] * inv) | ((unsigned)f2bf(p[3] * inv) << 16);
        *(uint2*)(aggbf + (size_t)snode[s] * 128 + qd * 4) = pk;
    }
}

// ------- fused gate + residual + LayerNorm + next-layer msg MLP (layers 0-2) ----
__global__ void __launch_bounds__(256)
k_gatemlp(ushort* __restrict__ hbf, const ushort* __restrict__ aggbf,
          const ushort* __restrict__ GWt, const float* __restrict__ GB,
          const float* __restrict__ LNG, const float* __restrict__ LNB,
          const ushort* __restrict__ W1t, const float* __restrict__ B1,
          const ushort* __restrict__ W2t, const float* __restrict__ B2,
          ushort* __restrict__ mbf) {
    __shared__ ushort sA[64 * 136];
    const int tid = threadIdx.x;
    const int w = tid >> 6, lane = tid & 63, lr = lane & 15, lg = lane >> 4;
    const int row = blockIdx.x * 64 + w * 16 + lr;

    bfrag bvv[8];
    uint2 hp[8], ap[8];
#pragma unroll
    for (int kb = 0; kb < 4; ++kb)
        bvv[kb] = *(const bfrag*)(hbf + (size_t)row * 128 + kb * 32 + lg * 8);
#pragma unroll
    for (int kb = 0; kb < 4; ++kb)
        bvv[4 + kb] = *(const bfrag*)(aggbf + (size_t)row * 128 + kb * 32 + lg * 8);
#pragma unroll
    for (int t = 0; t < 8; ++t) {
        hp[t] = *(const uint2*)(hbf + (size_t)row * 128 + t * 16 + lg * 4);
        ap[t] = *(const uint2*)(aggbf + (size_t)row * 128 + t * 16 + lg * 4);
    }

    floatx4 acc[8];
#pragma unroll
    for (int t = 0; t < 8; ++t) acc[t] = (floatx4){0.f, 0.f, 0.f, 0.f};
#pragma unroll
    for (int kb = 0; kb < 8; ++kb) {
#pragma unroll
        for (int t = 0; t < 8; ++t) {
            bfrag av = *(const bfrag*)(GWt + (t * 16 + lr) * 256 + kb * 32 + lg * 8);
            acc[t] = MFMA(av, bvv[kb], acc[t]);
        }
    }
    float o[8][4];
    float s = 0.0f;
#pragma unroll
    for (int t = 0; t < 8; ++t) {
        const int c0 = t * 16 + lg * 4;
        const float4 gb = *(const float4*)(GB + c0);
        float h0 = bf2f((ushort)(hp[t].x & 0xFFFF)), h1 = bf2f((ushort)(hp[t].x >> 16));
        float h2 = bf2f((ushort)(hp[t].y & 0xFFFF)), h3 = bf2f((ushort)(hp[t].y >> 16));
        float a0 = bf2f((ushort)(ap[t].x & 0xFFFF)), a1 = bf2f((ushort)(ap[t].x >> 16));
        float a2 = bf2f((ushort)(ap[t].y & 0xFFFF)), a3 = bf2f((ushort)(ap[t].y >> 16));
        o[t][0] = h0 + sigm(acc[t][0] + gb.x) * a0;
        o[t][1] = h1 + sigm(acc[t][1] + gb.y) * a1;
        o[t][2] = h2 + sigm(acc[t][2] + gb.z) * a2;
        o[t][3] = h3 + sigm(acc[t][3] + gb.w) * a3;
        s += o[t][0] + o[t][1] + o[t][2] + o[t][3];
    }
    s += __shfl_xor(s, 16);
    s += __shfl_xor(s, 32);
    const float mu = s * (1.0f / 128.0f);
    float q = 0.0f;
#pragma unroll
    for (int t = 0; t < 8; ++t)
#pragma unroll
        for (int r = 0; r < 4; ++r) {
            float dx = o[t][r] - mu;
            q = fmaf(dx, dx, q);
        }
    q += __shfl_xor(q, 16);
    q += __shfl_xor(q, 32);
    const float rs = rsqrtf(q * (1.0f / 128.0f) + 1e-5f);

    ushort* sArow = sA + (w * 16 + lr) * 136;
#pragma unroll
    for (int t = 0; t < 8; ++t) {
        const int c0 = t * 16 + lg * 4;
        const float4 g4 = *(const float4*)(LNG + c0);
        const float4 b4 = *(const float4*)(LNB + c0);
        float r0 = fmaf((o[t][0] - mu) * rs, g4.x, b4.x);
        float r1 = fmaf((o[t][1] - mu) * rs, g4.y, b4.y);
        float r2 = fmaf((o[t][2] - mu) * rs, g4.z, b4.z);
        float r3 = fmaf((o[t][3] - mu) * rs, g4.w, b4.w);
        uint2 pk;
        pk.x = (unsigned)f2bf(r0) | ((unsigned)f2bf(r1) << 16);
        pk.y = (unsigned)f2bf(r2) | ((unsigned)f2bf(r3) << 16);
        if (row < NN) *(uint2*)(hbf + (size_t)row * 128 + c0) = pk;
        *(uint2*)(sArow + c0) = pk;
    }

    // msg G1 swapped
#pragma unroll
    for (int t = 0; t < 8; ++t) acc[t] = (floatx4){0.f, 0.f, 0.f, 0.f};
#pragma unroll
    for (int kb = 0; kb < 4; ++kb) {
        bfrag bv = *(const bfrag*)(sArow + kb * 32 + lg * 8);
#pragma unroll
        for (int t = 0; t < 8; ++t) {
            bfrag av = *(const bfrag*)(W1t + (t * 16 + lr) * 128 + kb * 32 + lg * 8);
            acc[t] = MFMA(av, bv, acc[t]);
        }
    }
#pragma unroll
    for (int t = 0; t < 8; ++t) {
        const float4 b1 = *(const float4*)(B1 + t * 16 + lg * 4);
        float h0 = gelu_t(acc[t][0] + b1.x), h1 = gelu_t(acc[t][1] + b1.y);
        float h2 = gelu_t(acc[t][2] + b1.z), h3 = gelu_t(acc[t][3] + b1.w);
        uint2 p;
        p.x = (unsigned)f2bf(h0) | ((unsigned)f2bf(h1) << 16);
        p.y = (unsigned)f2bf(h2) | ((unsigned)f2bf(h3) << 16);
        *(uint2*)(sArow + t * 16 + lg * 4) = p;
    }
    // msg G2 swapped -> coalesced mbf
#pragma unroll
    for (int t = 0; t < 8; ++t) acc[t] = (floatx4){0.f, 0.f, 0.f, 0.f};
#pragma unroll
    for (int kb = 0; kb < 4; ++kb) {
        bfrag av = *(const bfrag*)(sArow + kb * 32 + lg * 8);
#pragma unroll
        for (int t = 0; t < 8; ++t) {
            bfrag bw = *(const bfrag*)(W2t + (t * 16 + lr) * 128 + kb * 32 + lg * 8);
            acc[t] = MFMA(bw, av, acc[t]);
        }
    }
    if (row < NN) {
        ushort* orow = mbf + (size_t)row * 128;
#pragma unroll
        for (int t = 0; t < 8; ++t) {
            const float4 b2 = *(const float4*)(B2 + t * 16 + lg * 4);
            uint2 p;
            p.x = (unsigned)f2bf(acc[t][0] + b2.x) |
                  ((unsigned)f2bf(acc[t][1] + b2.y) << 16);
            p.y = (unsigned)f2bf(acc[t][2] + b2.z) |
                  ((unsigned)f2bf(acc[t][3] + b2.w) << 16);
            *(uint2*)(orow + t * 16 + lg * 4) = p;
        }
    }
}

// ------- last layer: gate + residual + LN + 3 heads fused ----
__global__ void __launch_bounds__(256)
k_gateheads(const ushort* __restrict__ hbf, const ushort* __restrict__ aggbf,
            const ushort* __restrict__ GWt, const float* __restrict__ GB,
            const float* __restrict__ LNG, const float* __restrict__ LNB,
            const ushort* __restrict__ WHt, float* __restrict__ OUT,
            const float* __restrict__ b1a, const float* __restrict__ b1b,
            const float* __restrict__ b1c,
            const float* __restrict__ w2a, const float* __restrict__ w2b,
            const float* __restrict__ w2c,
            const float* __restrict__ b2a, const float* __restrict__ b2b,
            const float* __restrict__ b2c) {
    __shared__ ushort sA[64 * 136];
    const int tid = threadIdx.x;
    const int w = tid >> 6, lane = tid & 63, lr = lane & 15, lg = lane >> 4;
    const int row = blockIdx.x * 64 + w * 16 + lr;

    bfrag bvv[8];
    uint2 hp[8], ap[8];
#pragma unroll
    for (int kb = 0; kb < 4; ++kb)
        bvv[kb] = *(const bfrag*)(hbf + (size_t)row * 128 + kb * 32 + lg * 8);
#pragma unroll
    for (int kb = 0; kb < 4; ++kb)
        bvv[4 + kb] = *(const bfrag*)(aggbf + (size_t)row * 128 + kb * 32 + lg * 8);
#pragma unroll
    for (int t = 0; t < 8; ++t) {
        hp[t] = *(const uint2*)(hbf + (size_t)row * 128 + t * 16 + lg * 4);
        ap[t] = *(const uint2*)(aggbf + (size_t)row * 128 + t * 16 + lg * 4);
    }

    floatx4 acc[8];
#pragma unroll
    for (int t = 0; t < 8; ++t) acc[t] = (floatx4){0.f, 0.f, 0.f, 0.f};
#pragma unroll
    for (int kb = 0; kb < 8; ++kb) {
#pragma unroll
        for (int t = 0; t < 8; ++t) {
            bfrag av = *(const bfrag*)(GWt + (t * 16 + lr) * 256 + kb * 32 + lg * 8);
            acc[t] = MFMA(av, bvv[kb], acc[t]);
        }
    }
    float o[8][4];
    float s = 0.0f;
#pragma unroll
    for (int t = 0; t < 8; ++t) {
        const int c0 = t * 16 + lg * 4;
        const float4 gb = *(const float4*)(GB + c0);
        float h0 = bf2f((ushort)(hp[t].x & 0xFFFF)), h1 = bf2f((ushort)(hp[t].x >> 16));
        float h2 = bf2f((ushort)(hp[t].y & 0xFFFF)), h3 = bf2f((ushort)(hp[t].y >> 16));
        float a0 = bf2f((ushort)(ap[t].x & 0xFFFF)), a1 = bf2f((ushort)(ap[t].x >> 16));
        float a2 = bf2f((ushort)(ap[t].y & 0xFFFF)), a3 = bf2f((ushort)(ap[t].y >> 16));
        o[t][0] = h0 + sigm(acc[t][0] + gb.x) * a0;
        o[t][1] = h1 + sigm(acc[t][1] + gb.y) * a1;
        o[t][2] = h2 + sigm(acc[t][2] + gb.z) * a2;
        o[t][3] = h3 + sigm(acc[t][3] + gb.w) * a3;
        s += o[t][0] + o[t][1] + o[t][2] + o[t][3];
    }
    s += __shfl_xor(s, 16);
    s += __shfl_xor(s, 32);
    const float mu = s * (1.0f / 128.0f);
    float q = 0.0f;
#pragma unroll
    for (int t = 0; t < 8; ++t)
#pragma unroll
        for (int r = 0; r < 4; ++r) {
            float dx = o[t][r] - mu;
            q = fmaf(dx, dx, q);
        }
    q += __shfl_xor(q, 16);
    q += __shfl_xor(q, 32);
    const float rs = rsqrtf(q * (1.0f / 128.0f) + 1e-5f);

    ushort* sArow = sA + (w * 16 + lr) * 136;
#pragma unroll
    for (int t = 0; t < 8; ++t) {
        const int c0 = t * 16 + lg * 4;
        const float4 g4 = *(const float4*)(LNG + c0);
        const float4 b4 = *(const float4*)(LNB + c0);
        float r0 = fmaf((o[t][0] - mu) * rs, g4.x, b4.x);
        float r1 = fmaf((o[t][1] - mu) * rs, g4.y, b4.y);
        float r2 = fmaf((o[t][2] - mu) * rs, g4.z, b4.z);
        float r3 = fmaf((o[t][3] - mu) * rs, g4.w, b4.w);
        uint2 pk;
        pk.x = (unsigned)f2bf(r0) | ((unsigned)f2bf(r1) << 16);
        pk.y = (unsigned)f2bf(r2) | ((unsigned)f2bf(r3) << 16);
        *(uint2*)(sArow + c0) = pk;
    }

    floatx4 acc2[12];
#pragma unroll
    for (int t = 0; t < 12; ++t) acc2[t] = (floatx4){0.f, 0.f, 0.f, 0.f};
#pragma unroll
    for (int kb = 0; kb < 4; ++kb) {
        bfrag bv = *(const bfrag*)(sArow + kb * 32 + lg * 8);
#pragma unroll
        for (int t = 0; t < 12; ++t) {
            bfrag av = *(const bfrag*)(WHt + (t * 16 + lr) * 128 + kb * 32 + lg * 8);
            acc2[t] = MFMA(av, bv, acc2[t]);
        }
    }
    const float* b1s[3] = {b1a, b1b, b1c};
    const float* w2s[3] = {w2a, w2b, w2c};
    float p[3] = {0.f, 0.f, 0.f};
#pragma unroll
    for (int t = 0; t < 12; ++t) {
        const int head = t >> 2;
        const int c0 = (t & 3) * 16 + lg * 4;
        const float4 b1 = *(const float4*)(b1s[head] + c0);
        const float4 w2 = *(const float4*)(w2s[head] + c0);
        p[head] += gelu_t(acc2[t][0] + b1.x) * w2.x;
        p[head] += gelu_t(acc2[t][1] + b1.y) * w2.y;
        p[head] += gelu_t(acc2[t][2] + b1.z) * w2.z;
        p[head] += gelu_t(acc2[t][3] + b1.w) * w2.w;
    }
#pragma unroll
    for (int hd = 0; hd < 3; ++hd) {
        p[hd] += __shfl_xor(p[hd], 16);
        p[hd] += __shfl_xor(p[hd], 32);
    }
    if (lg == 0 && row < NN) {
        OUT[0 * NN + row] = p[0] + b2a[0];
        OUT[1 * NN + row] = p[1] + b2b[0];
        OUT[2 * NN + row] = p[2] + b2c[0];
    }
}

extern "C" void kernel_launch(void* const* d_in, const int* in_sizes, int n_in,
                              void* d_out, int out_size, void* d_ws, size_t ws_size,
                              hipStream_t stream) {
    const float* x       = (const float*)d_in[0];
    const int*   ei      = (const int*)d_in[1];
    const float* ea      = (const float*)d_in[2];
    const float* enc_w1  = (const float*)d_in[3];
    const float* enc_b1  = (const float*)d_in[4];
    const float* enc_w2  = (const float*)d_in[5];
    const float* enc_b2  = (const float*)d_in[6];
    const float* edge_w1 = (const float*)d_in[7];
    const float* edge_b1 = (const float*)d_in[8];
    const float* edge_w2 = (const float*)d_in[9];
    const float* edge_b2 = (const float*)d_in[10];
    const float* msg_w1  = (const float*)d_in[11];
    const float* msg_b1  = (const float*)d_in[12];
    const float* msg_w2  = (const float*)d_in[13];
    const float* msg_b2  = (const float*)d_in[14];
    const float* gate_w  = (const float*)d_in[15];
    const float* gate_b  = (const float*)d_in[16];
    const float* ln_g    = (const float*)d_in[17];
    const float* ln_b    = (const float*)d_in[18];
    const float* hw[12];
    for (int t = 0; t < 12; ++t) hw[t] = (const float*)d_in[19 + t];

    const size_t NNH = (size_t)NN2 * H;
    ushort* hbf   = (ushort*)d_ws;
    ushort* mbf   = hbf + NNH;
    ushort* aggbf = mbf + NNH;
    ushort* xbf   = aggbf + NNH;                   // NN2*32
    ushort* eapbf = xbf + (size_t)NN2 * 32;        // NE*16 (permuted)
    ushort* wt    = eapbf + (size_t)NE * 16;
    ushort* wt_enc1 = wt;                          // 128*32
    ushort* wt_enc2 = wt_enc1 + 128 * 32;          // 128*128
    ushort* wt_e1   = wt_enc2 + 128 * 128;         // 4*128*32
    ushort* wt_e2   = wt_e1 + 4 * 128 * 32;        // 4*128*128
    ushort* wt_m1   = wt_e2 + 4 * 128 * 128;       // 4*128*128
    ushort* wt_m2   = wt_m1 + 4 * 128 * 128;       // 4*128*128
    ushort* wt_g    = wt_m2 + 4 * 128 * 128;       // 4*128*256
    ushort* wt_h    = wt_g + 4 * 128 * 256;        // 192*128
    int* row_ptr = (int*)(wt_h + 192 * 128 + 64);
    int* perm    = row_ptr + 100352;
    int* nf      = perm + NE;
    int* nl      = nf + 10240;
    int* hist    = nl + 10240;
    int* incl    = hist + 100352;
    int* cursor  = incl + 100352;
    int* bsum    = cursor + 100352;
    uintptr_t ewp_addr = ((uintptr_t)(bsum + 512) + 15) & ~(uintptr_t)15;
    ushort* ewp = (ushort*)ewp_addr;
    const size_t used = ewp_addr - (uintptr_t)d_ws;

    int P = 4;
    size_t rows = NE / 4 + 1024;
    if (ws_size >= used + (size_t)NE * 128 * 2) { P = 1; rows = NE; }
    else if (ws_size >= used + ((size_t)NE / 2 + 1024) * 128 * 2) { P = 2; rows = NE / 2 + 1024; }
    const int PE = NE / P;
    const int NGB = 10000 / P;
    const int ewblk = (int)(rows / 128);

    // ---- ONE cooperative prep kernel: init+hist+scan+scatter+blockrange+cvtperm ----
    {
        void* args[] = {
            (void*)&ei, (void*)&ea, (void*)&hist, (void*)&incl, (void*)&bsum,
            (void*)&row_ptr, (void*)&cursor, (void*)&perm, (void*)&nf, (void*)&nl,
            (void*)&eapbf, (void*)&aggbf
        };
        hipLaunchCooperativeKernel((const void*)k_prep, dim3(1024), dim3(256),
                                   args, 0, stream);
    }

    // ---- all weight transposes + x convert, one launch ----
    k_wtall<<<14024, 256, 0, stream>>>(wt, xbf, x, enc_w1, enc_w2, edge_w1, edge_w2,
                                       msg_w1, msg_w2, gate_w, hw[0], hw[4], hw[8]);

    // ---- network ----
    const int ntiles = NN2 / 64;
    k_encmsg<<<ntiles, 256, 0, stream>>>(xbf, hbf, mbf,
        wt_enc1, enc_b1, wt_enc2, enc_b2,
        wt_m1, msg_b1, wt_m2, msg_b2);

    for (int l = 0; l < NL; ++l) {
        for (int p = 0; p < P; ++p) {
            const int S = p * PE;
            k_ew<<<ewblk, 256, 0, stream>>>(eapbf, ewp, S,
                wt_e1 + (size_t)l * 128 * 32, edge_b1 + l * H,
                wt_e2 + (size_t)l * 128 * 128, edge_b2 + l * H);
            const int nb = (p == P - 1) ? (NGB + 1) : NGB;
            k_gms<<<nb, 256, 0, stream>>>(ei, perm, row_ptr,
                nf + p * NGB, nl + p * NGB, ewp, S, mbf, aggbf);
        }
        if (l < NL - 1) {
            k_gatemlp<<<ntiles, 256, 0, stream>>>(hbf, aggbf,
                wt_g + (size_t)l * 128 * 256, gate_b + l * H,
                ln_g + l * H, ln_b + l * H,
                wt_m1 + (size_t)(l + 1) * 128 * 128, msg_b1 + (l + 1) * H,
                wt_m2 + (size_t)(l + 1) * 128 * 128, msg_b2 + (l + 1) * H, mbf);
        } else {
            k_gateheads<<<ntiles, 256, 0, stream>>>(hbf, aggbf,
                wt_g + (size_t)l * 128 * 256, gate_b + l * H,
                ln_g + l * H, ln_b + l * H,
                wt_h, (float*)d_out,
                hw[1], hw[5], hw[9], hw[2], hw[6], hw[10], hw[3], hw[7], hw[11]);
        }
    }
}

// Round 15
// 2192.443 us; speedup vs baseline: 1.2828x; 1.2828x over previous
//
#include <hip/hip_runtime.h>
#include <math.h>

#define NN 100000
#define NN2 100032               // padded to 64 rows
#define NE 640000
#define H 128
#define AD 25
#define ED 10
#define RD 64
#define NL 4
#define NB_E (NE / 64 + 1)       // 10001 edge blocks
#define NSB ((NN + 255) / 256)   // 391 scan blocks
#define CAP 256

typedef short bfrag __attribute__((ext_vector_type(8)));
typedef float floatx4 __attribute__((ext_vector_type(4)));
typedef unsigned short ushort;

#define MFMA(a, b, c) __builtin_amdgcn_mfma_f32_16x16x32_bf16(a, b, c, 0, 0, 0)

__device__ __forceinline__ ushort f2bf(float f) {
    unsigned u = __float_as_uint(f);
    unsigned r = (u + 0x7FFFu + ((u >> 16) & 1u)) >> 16;
    return (ushort)r;
}
__device__ __forceinline__ float bf2f(ushort b) {
    return __uint_as_float(((unsigned)b) << 16);
}
__device__ __forceinline__ float gelu_t(float x) {
    float u = 0.7978845608028654f * (x + 0.044715f * x * x * x);
    float e = __expf(2.0f * u);
    float th = 1.0f - 2.0f / (e + 1.0f);
    return 0.5f * x * (1.0f + th);
}
__device__ __forceinline__ float sigm(float x) {
    return 1.0f / (1.0f + __expf(-x));
}

// ---------------- ALL weight transposes + x convert in ONE launch ----------------
__global__ void k_wtall(ushort* __restrict__ wt, ushort* __restrict__ xbf,
                        const float* __restrict__ x,
                        const float* __restrict__ s0, const float* __restrict__ s1,
                        const float* __restrict__ s2, const float* __restrict__ s3,
                        const float* __restrict__ s4, const float* __restrict__ s5,
                        const float* __restrict__ s6, const float* __restrict__ s7,
                        const float* __restrict__ s8, const float* __restrict__ s9) {
    int idx = blockIdx.x * 256 + threadIdx.x;
    if (idx >= 389120) {
        int lidx = idx - 389120;
        if (lidx >= NN2 * 32) return;
        int r = lidx >> 5, k = lidx & 31;
        xbf[lidx] = (r < NN && k < 25) ? f2bf(x[(size_t)r * 25 + k]) : 0;
        return;
    }
    const float* src;
    int Ks, N, Kd, off;
    if (idx < 4096)        { src = s0; Ks = 25;  N = 128; Kd = 32;  off = 0; }
    else if (idx < 20480)  { src = s1; Ks = 128; N = 128; Kd = 128; off = 4096; }
    else if (idx < 36864)  { src = s2; Ks = 10;  N = 128; Kd = 32;  off = 20480; }
    else if (idx < 102400) { src = s3; Ks = 128; N = 128; Kd = 128; off = 36864; }
    else if (idx < 167936) { src = s4; Ks = 128; N = 128; Kd = 128; off = 102400; }
    else if (idx < 233472) { src = s5; Ks = 128; N = 128; Kd = 128; off = 167936; }
    else if (idx < 364544) { src = s6; Ks = 256; N = 128; Kd = 256; off = 233472; }
    else if (idx < 372736) { src = s7; Ks = 128; N = 64;  Kd = 128; off = 364544; }
    else if (idx < 380928) { src = s8; Ks = 128; N = 64;  Kd = 128; off = 372736; }
    else                   { src = s9; Ks = 128; N = 64;  Kd = 128; off = 380928; }
    int lidx = idx - off;
    int nk = N * Kd;
    int b = lidx / nk;
    int rem = lidx - b * nk;
    int n = rem / Kd, k = rem - n * Kd;
    float v = (k < Ks) ? src[((size_t)b * Ks + k) * N + n] : 0.0f;
    wt[idx] = f2bf(v);
}

__global__ void k_cvtperm(const float* __restrict__ ea, const int* __restrict__ perm,
                          ushort* __restrict__ out) {
    int j = blockIdx.x * 256 + threadIdx.x;
    if (j >= NE) return;
    const float* src = ea + (size_t)perm[j] * ED;
    unsigned u[8];
#pragma unroll
    for (int k = 0; k < 5; ++k)
        u[k] = (unsigned)f2bf(src[2 * k]) | ((unsigned)f2bf(src[2 * k + 1]) << 16);
    u[5] = u[6] = u[7] = 0u;
    uint4* o = (uint4*)(out + (size_t)j * 16);
    uint4 a; a.x = u[0]; a.y = u[1]; a.z = u[2]; a.w = u[3];
    uint4 b; b.x = u[4]; b.y = u[5]; b.z = u[6]; b.w = u[7];
    o[0] = a; o[1] = b;
}

// ---------------- sort infrastructure (proven, separate kernels) ----------------
__global__ void k_init3(int* __restrict__ hist, int* __restrict__ nf,
                        int* __restrict__ nl) {
    int i = blockIdx.x * 256 + threadIdx.x;
    if (i < NN) hist[i] = 0;
    if (i < NB_E) { nf[i] = 0x7fffffff; nl[i] = -1; }
}
__global__ void k_hist(const int* __restrict__ ei, int* __restrict__ hist) {
    int e = blockIdx.x * 256 + threadIdx.x;
    if (e < NE) atomicAdd(&hist[ei[NE + e]], 1);
}
__global__ void k_scan1(const int* __restrict__ hist, int* __restrict__ incl,
                        int* __restrict__ bsum) {
    __shared__ int s[256];
    int tid = threadIdx.x;
    int i = blockIdx.x * 256 + tid;
    s[tid] = (i < NN) ? hist[i] : 0;
    __syncthreads();
    for (int off = 1; off < 256; off <<= 1) {
        int t = (tid >= off) ? s[tid - off] : 0;
        __syncthreads();
        s[tid] += t;
        __syncthreads();
    }
    if (i < NN) incl[i] = s[tid];
    if (tid == 255) bsum[blockIdx.x] = s[255];
}
__global__ void k_scan2(int* __restrict__ bsum) {
    __shared__ int s[512];
    int tid = threadIdx.x;
    s[tid] = (tid < NSB) ? bsum[tid] : 0;
    __syncthreads();
    for (int off = 1; off < 512; off <<= 1) {
        int t = (tid >= off) ? s[tid - off] : 0;
        __syncthreads();
        s[tid] += t;
        __syncthreads();
    }
    if (tid < NSB) bsum[tid] = (tid > 0) ? s[tid - 1] : 0;
}
__global__ void k_scan3(const int* __restrict__ hist, const int* __restrict__ incl,
                        const int* __restrict__ bsum, int* __restrict__ row_ptr,
                        int* __restrict__ cursor) {
    int i = blockIdx.x * 256 + threadIdx.x;
    if (i < NN) {
        int rp = bsum[blockIdx.x] + incl[i] - hist[i];
        row_ptr[i] = rp;
        cursor[i] = rp;
    }
    if (i == 0) row_ptr[NN] = NE;
}
__global__ void k_scatter(const int* __restrict__ ei, int* __restrict__ cursor,
                          int* __restrict__ perm) {
    int e = blockIdx.x * 256 + threadIdx.x;
    if (e < NE) {
        int d = ei[NE + e];
        int pos = atomicAdd(&cursor[d], 1);
        perm[pos] = e;
    }
}
__global__ void k_blockrange(const int* __restrict__ row_ptr, int* __restrict__ nf,
                             int* __restrict__ nl) {
    int n = blockIdx.x * 256 + threadIdx.x;
    if (n < NN) {
        int b = row_ptr[n] >> 6;
        atomicMin(&nf[b], n);
        atomicMax(&nl[b], n);
    }
}

// ---- FUSED encoder MLP2 + layer-0 msg MLP2 (wave-local sH reuse, swapped G2) ----
__global__ void __launch_bounds__(256)
k_encmsg(const ushort* __restrict__ xbf, ushort* __restrict__ hbf,
         ushort* __restrict__ mbf,
         const ushort* __restrict__ EW1t, const float* __restrict__ EB1,
         const ushort* __restrict__ EW2t, const float* __restrict__ EB2,
         const ushort* __restrict__ MW1t, const float* __restrict__ MB1,
         const ushort* __restrict__ MW2t, const float* __restrict__ MB2) {
    __shared__ ushort sH[64 * 136];
    const int tid = threadIdx.x;
    const int w = tid >> 6, lane = tid & 63, lr = lane & 15, lg = lane >> 4;
    const int rowB = blockIdx.x * 64 + w * 16 + lr;
    ushort* sHrow = sH + (w * 16 + lr) * 136;

    bfrag bv0 = *(const bfrag*)(xbf + (size_t)rowB * 32 + lg * 8);
    floatx4 acc[8];
#pragma unroll
    for (int t = 0; t < 8; ++t) acc[t] = (floatx4){0.f, 0.f, 0.f, 0.f};
#pragma unroll
    for (int t = 0; t < 8; ++t) {
        bfrag av = *(const bfrag*)(EW1t + (t * 16 + lr) * 32 + lg * 8);
        acc[t] = MFMA(av, bv0, acc[t]);
    }
#pragma unroll
    for (int t = 0; t < 8; ++t) {
        const float4 b1 = *(const float4*)(EB1 + t * 16 + lg * 4);
        float h0 = gelu_t(acc[t][0] + b1.x), h1 = gelu_t(acc[t][1] + b1.y);
        float h2 = gelu_t(acc[t][2] + b1.z), h3 = gelu_t(acc[t][3] + b1.w);
        uint2 p;
        p.x = (unsigned)f2bf(h0) | ((unsigned)f2bf(h1) << 16);
        p.y = (unsigned)f2bf(h2) | ((unsigned)f2bf(h3) << 16);
        *(uint2*)(sHrow + t * 16 + lg * 4) = p;
    }
#pragma unroll
    for (int t = 0; t < 8; ++t) acc[t] = (floatx4){0.f, 0.f, 0.f, 0.f};
#pragma unroll
    for (int kb = 0; kb < 4; ++kb) {
        bfrag av = *(const bfrag*)(sHrow + kb * 32 + lg * 8);
#pragma unroll
        for (int t = 0; t < 8; ++t) {
            bfrag bw = *(const bfrag*)(EW2t + (t * 16 + lr) * 128 + kb * 32 + lg * 8);
            acc[t] = MFMA(bw, av, acc[t]);
        }
    }
#pragma unroll
    for (int t = 0; t < 8; ++t) {
        const float4 b2 = *(const float4*)(EB2 + t * 16 + lg * 4);
        uint2 p;
        p.x = (unsigned)f2bf(acc[t][0] + b2.x) |
              ((unsigned)f2bf(acc[t][1] + b2.y) << 16);
        p.y = (unsigned)f2bf(acc[t][2] + b2.z) |
              ((unsigned)f2bf(acc[t][3] + b2.w) << 16);
        if (rowB < NN) *(uint2*)(hbf + (size_t)rowB * 128 + t * 16 + lg * 4) = p;
        *(uint2*)(sHrow + t * 16 + lg * 4) = p;
    }
#pragma unroll
    for (int t = 0; t < 8; ++t) acc[t] = (floatx4){0.f, 0.f, 0.f, 0.f};
#pragma unroll
    for (int kb = 0; kb < 4; ++kb) {
        bfrag bv = *(const bfrag*)(sHrow + kb * 32 + lg * 8);
#pragma unroll
        for (int t = 0; t < 8; ++t) {
            bfrag av = *(const bfrag*)(MW1t + (t * 16 + lr) * 128 + kb * 32 + lg * 8);
            acc[t] = MFMA(av, bv, acc[t]);
        }
    }
#pragma unroll
    for (int t = 0; t < 8; ++t) {
        const float4 b1 = *(const float4*)(MB1 + t * 16 + lg * 4);
        float h0 = gelu_t(acc[t][0] + b1.x), h1 = gelu_t(acc[t][1] + b1.y);
        float h2 = gelu_t(acc[t][2] + b1.z), h3 = gelu_t(acc[t][3] + b1.w);
        uint2 p;
        p.x = (unsigned)f2bf(h0) | ((unsigned)f2bf(h1) << 16);
        p.y = (unsigned)f2bf(h2) | ((unsigned)f2bf(h3) << 16);
        *(uint2*)(sHrow + t * 16 + lg * 4) = p;
    }
#pragma unroll
    for (int t = 0; t < 8; ++t) acc[t] = (floatx4){0.f, 0.f, 0.f, 0.f};
#pragma unroll
    for (int kb = 0; kb < 4; ++kb) {
        bfrag av = *(const bfrag*)(sHrow + kb * 32 + lg * 8);
#pragma unroll
        for (int t = 0; t < 8; ++t) {
            bfrag bw = *(const bfrag*)(MW2t + (t * 16 + lr) * 128 + kb * 32 + lg * 8);
            acc[t] = MFMA(bw, av, acc[t]);
        }
    }
    if (rowB < NN) {
        ushort* orow = mbf + (size_t)rowB * 128;
#pragma unroll
        for (int t = 0; t < 8; ++t) {
            const float4 b2 = *(const float4*)(MB2 + t * 16 + lg * 4);
            uint2 p;
            p.x = (unsigned)f2bf(acc[t][0] + b2.x) |
                  ((unsigned)f2bf(acc[t][1] + b2.y) << 16);
            p.y = (unsigned)f2bf(acc[t][2] + b2.z) |
                  ((unsigned)f2bf(acc[t][3] + b2.w) << 16);
            *(uint2*)(orow + t * 16 + lg * 4) = p;
        }
    }
}

// ------ A: edge-weight GEMM (proven staged version, swapped G2) ----
__global__ void __launch_bounds__(256)
k_ew(const ushort* __restrict__ eap, ushort* __restrict__ ewp, int S,
     const ushort* __restrict__ W1t, const float* __restrict__ B1,
     const ushort* __restrict__ W2t, const float* __restrict__ B2) {
    __shared__ ushort sea[128 * 40];
    __shared__ ushort sH[4][16 * 136];
    const int tid = threadIdx.x;
    const int w = tid >> 6, lane = tid & 63, lr = lane & 15, lg = lane >> 4;
    const int jl0 = blockIdx.x * 128;

    {
        int r = tid >> 1, half = tid & 1;
        int j = S + jl0 + r;
        uint4 z; z.x = z.y = z.z = z.w = 0u;
        uint4 v = z;
        if (j < NE) v = *(const uint4*)(eap + (size_t)j * 16 + half * 8);
        *(uint4*)(sea + r * 40 + half * 8) = v;
        *(uint4*)(sea + r * 40 + 16 + half * 8) = z;
    }
    bfrag av1[8];
#pragma unroll
    for (int t = 0; t < 8; ++t)
        av1[t] = *(const bfrag*)(W1t + (t * 16 + lr) * 32 + lg * 8);
    __syncthreads();

    for (int rt = 0; rt < 2; ++rt) {
        const int row_l = w * 32 + rt * 16;
        floatx4 acc[8];
#pragma unroll
        for (int t = 0; t < 8; ++t) acc[t] = (floatx4){0.f, 0.f, 0.f, 0.f};
        bfrag bv = *(const bfrag*)(sea + (row_l + lr) * 40 + lg * 8);
#pragma unroll
        for (int t = 0; t < 8; ++t) acc[t] = MFMA(av1[t], bv, acc[t]);
        ushort* sHr = sH[w] + lr * 136;
#pragma unroll
        for (int t = 0; t < 8; ++t) {
            const float4 b1 = *(const float4*)(B1 + t * 16 + lg * 4);
            float h0 = gelu_t(acc[t][0] + b1.x), h1 = gelu_t(acc[t][1] + b1.y);
            float h2 = gelu_t(acc[t][2] + b1.z), h3 = gelu_t(acc[t][3] + b1.w);
            uint2 p;
            p.x = (unsigned)f2bf(h0) | ((unsigned)f2bf(h1) << 16);
            p.y = (unsigned)f2bf(h2) | ((unsigned)f2bf(h3) << 16);
            *(uint2*)(sHr + t * 16 + lg * 4) = p;
        }
#pragma unroll
        for (int t = 0; t < 8; ++t) acc[t] = (floatx4){0.f, 0.f, 0.f, 0.f};
#pragma unroll
        for (int kb = 0; kb < 4; ++kb) {
            bfrag av = *(const bfrag*)(sH[w] + lr * 136 + kb * 32 + lg * 8);
#pragma unroll
            for (int t = 0; t < 8; ++t) {
                bfrag bw = *(const bfrag*)(W2t + (t * 16 + lr) * 128 + kb * 32 + lg * 8);
                acc[t] = MFMA(bw, av, acc[t]);
            }
        }
        const int jl = jl0 + row_l + lr;
        if (S + jl < NE) {
            ushort* orow = ewp + (size_t)jl * 128;
#pragma unroll
            for (int t = 0; t < 8; ++t) {
                const float4 b2 = *(const float4*)(B2 + t * 16 + lg * 4);
                uint2 p;
                p.x = (unsigned)f2bf(acc[t][0] + b2.x) |
                      ((unsigned)f2bf(acc[t][1] + b2.y) << 16);
                p.y = (unsigned)f2bf(acc[t][2] + b2.z) |
                      ((unsigned)f2bf(acc[t][3] + b2.w) << 16);
                *(uint2*)(orow + t * 16 + lg * 4) = p;
            }
        }
    }
}

// ---------------- B: gather-multiply-segment-mean (2-deep prefetch) ----------
__global__ void __launch_bounds__(256)
k_gms(const int* __restrict__ ei, const int* __restrict__ perm,
      const int* __restrict__ row_ptr, const int* __restrict__ nf,
      const int* __restrict__ nl, const ushort* __restrict__ ewp, int S,
      const ushort* __restrict__ mbf, ushort* __restrict__ aggbf) {
    __shared__ int ssrc[CAP], sdst[CAP], sseg[CAP];
    __shared__ int snode[64];
    __shared__ float sinvd[64];
    __shared__ float sagg[64 * 132];
    __shared__ int swtot[4];
    __shared__ int s_nseg;

    const int b = blockIdx.x;
    const int n0 = nf[b];
    if (n0 >= NN) return;
    const int n1 = nl[b];
    const int e0 = row_ptr[n0];
    int ne = row_ptr[n1 + 1] - e0;
    if (ne <= 0) return;
    const int ncl = (ne < CAP) ? ne : CAP;

    const int tid = threadIdx.x;
    const int w = tid >> 6, lane = tid & 63;

    for (int i = tid; i < 64 * 132; i += 256) sagg[i] = 0.0f;

    int dstv = -1 - tid;
    if (tid < ncl) {
        int e = perm[e0 + tid];
        ssrc[tid] = ei[e];
        dstv = ei[NE + e];
    }
    sdst[tid] = dstv;
    __syncthreads();

    int f = 0;
    if (tid < ncl) f = (tid == 0) ? 1 : (sdst[tid] != sdst[tid - 1]);
    unsigned long long mk = __ballot(f);
    int incl = __popcll(mk & (~0ull >> (63 - lane)));
    if (lane == 63) swtot[w] = incl;
    __syncthreads();
    int woff = 0;
    for (int i = 0; i < w; ++i) woff += swtot[i];
    int segid = woff + incl;
    sseg[tid] = segid - 1;
    if (f) {
        int s = segid - 1;
        snode[s] = dstv;
        sinvd[s] = 1.0f / (float)(row_ptr[dstv + 1] - row_ptr[dstv]);
    }
    if (tid == 255) s_nseg = segid;
    __syncthreads();
    const int nseg = s_nseg;

    const int c0 = (tid & 31) * 4;
    const int g = tid >> 5;
    const int chunk = (ncl + 7) >> 3;
    const int j0 = g * chunk;
    const int j1 = (j0 + chunk < ncl) ? (j0 + chunk) : ncl;
    const int be = e0 - S;
    int cs = -1;
    float v0 = 0.f, v1 = 0.f, v2 = 0.f, v3 = 0.f;
    uint2 ewc, mvc;
    if (j0 < j1) {
        ewc = *(const uint2*)(ewp + (size_t)(be + j0) * 128 + c0);
        mvc = *(const uint2*)(mbf + (size_t)ssrc[j0] * 128 + c0);
    }
    for (int j = j0; j < j1; ++j) {
        uint2 ewn = ewc, mvn = mvc;
        if (j + 1 < j1) {
            ewn = *(const uint2*)(ewp + (size_t)(be + j + 1) * 128 + c0);
            mvn = *(const uint2*)(mbf + (size_t)ssrc[j + 1] * 128 + c0);
        }
        float a0 = bf2f((ushort)(ewc.x & 0xFFFF)) * bf2f((ushort)(mvc.x & 0xFFFF));
        float a1 = bf2f((ushort)(ewc.x >> 16)) * bf2f((ushort)(mvc.x >> 16));
        float a2 = bf2f((ushort)(ewc.y & 0xFFFF)) * bf2f((ushort)(mvc.y & 0xFFFF));
        float a3 = bf2f((ushort)(ewc.y >> 16)) * bf2f((ushort)(mvc.y >> 16));
        int sg = sseg[j];
        if (sg != cs) {
            if (cs >= 0) {
                float* p = &sagg[cs * 132 + c0];
                atomicAdd(p + 0, v0); atomicAdd(p + 1, v1);
                atomicAdd(p + 2, v2); atomicAdd(p + 3, v3);
            }
            cs = sg; v0 = a0; v1 = a1; v2 = a2; v3 = a3;
        } else {
            v0 += a0; v1 += a1; v2 += a2; v3 += a3;
        }
        ewc = ewn; mvc = mvn;
    }
    if (cs >= 0) {
        float* p = &sagg[cs * 132 + c0];
        atomicAdd(p + 0, v0); atomicAdd(p + 1, v1);
        atomicAdd(p + 2, v2); atomicAdd(p + 3, v3);
    }
    __syncthreads();
    for (int i = tid; i < nseg * 32; i += 256) {
        int s = i >> 5, qd = i & 31;
        float inv = sinvd[s];
        const float* p = &sagg[s * 132 + qd * 4];
        uint2 pk;
        pk.x = (unsigned)f2bf(p[0] * inv) | ((unsigned)f2bf(p[1] * inv) << 16);
        pk.y = (unsigned)f2bf(p[2] * inv) | ((unsigned)f2bf(p[3] * inv) << 16);
        *(uint2*)(aggbf + (size_t)snode[s] * 128 + qd * 4) = pk;
    }
}

// ------- fused gate + residual + LayerNorm + next-layer msg MLP (layers 0-2) ----
__global__ void __launch_bounds__(256)
k_gatemlp(ushort* __restrict__ hbf, const ushort* __restrict__ aggbf,
          const ushort* __restrict__ GWt, const float* __restrict__ GB,
          const float* __restrict__ LNG, const float* __restrict__ LNB,
          const ushort* __restrict__ W1t, const float* __restrict__ B1,
          const ushort* __restrict__ W2t, const float* __restrict__ B2,
          ushort* __restrict__ mbf) {
    __shared__ ushort sA[64 * 136];
    const int tid = threadIdx.x;
    const int w = tid >> 6, lane = tid & 63, lr = lane & 15, lg = lane >> 4;
    const int row = blockIdx.x * 64 + w * 16 + lr;

    bfrag bvv[8];
    uint2 hp[8], ap[8];
#pragma unroll
    for (int kb = 0; kb < 4; ++kb)
        bvv[kb] = *(const bfrag*)(hbf + (size_t)row * 128 + kb * 32 + lg * 8);
#pragma unroll
    for (int kb = 0; kb < 4; ++kb)
        bvv[4 + kb] = *(const bfrag*)(aggbf + (size_t)row * 128 + kb * 32 + lg * 8);
#pragma unroll
    for (int t = 0; t < 8; ++t) {
        hp[t] = *(const uint2*)(hbf + (size_t)row * 128 + t * 16 + lg * 4);
        ap[t] = *(const uint2*)(aggbf + (size_t)row * 128 + t * 16 + lg * 4);
    }

    floatx4 acc[8];
#pragma unroll
    for (int t = 0; t < 8; ++t) acc[t] = (floatx4){0.f, 0.f, 0.f, 0.f};
#pragma unroll
    for (int kb = 0; kb < 8; ++kb) {
#pragma unroll
        for (int t = 0; t < 8; ++t) {
            bfrag av = *(const bfrag*)(GWt + (t * 16 + lr) * 256 + kb * 32 + lg * 8);
            acc[t] = MFMA(av, bvv[kb], acc[t]);
        }
    }
    float o[8][4];
    float s = 0.0f;
#pragma unroll
    for (int t = 0; t < 8; ++t) {
        const int c0 = t * 16 + lg * 4;
        const float4 gb = *(const float4*)(GB + c0);
        float h0 = bf2f((ushort)(hp[t].x & 0xFFFF)), h1 = bf2f((ushort)(hp[t].x >> 16));
        float h2 = bf2f((ushort)(hp[t].y & 0xFFFF)), h3 = bf2f((ushort)(hp[t].y >> 16));
        float a0 = bf2f((ushort)(ap[t].x & 0xFFFF)), a1 = bf2f((ushort)(ap[t].x >> 16));
        float a2 = bf2f((ushort)(ap[t].y & 0xFFFF)), a3 = bf2f((ushort)(ap[t].y >> 16));
        o[t][0] = h0 + sigm(acc[t][0] + gb.x) * a0;
        o[t][1] = h1 + sigm(acc[t][1] + gb.y) * a1;
        o[t][2] = h2 + sigm(acc[t][2] + gb.z) * a2;
        o[t][3] = h3 + sigm(acc[t][3] + gb.w) * a3;
        s += o[t][0] + o[t][1] + o[t][2] + o[t][3];
    }
    s += __shfl_xor(s, 16);
    s += __shfl_xor(s, 32);
    const float mu = s * (1.0f / 128.0f);
    float q = 0.0f;
#pragma unroll
    for (int t = 0; t < 8; ++t)
#pragma unroll
        for (int r = 0; r < 4; ++r) {
            float dx = o[t][r] - mu;
            q = fmaf(dx, dx, q);
        }
    q += __shfl_xor(q, 16);
    q += __shfl_xor(q, 32);
    const float rs = rsqrtf(q * (1.0f / 128.0f) + 1e-5f);

    ushort* sArow = sA + (w * 16 + lr) * 136;
#pragma unroll
    for (int t = 0; t < 8; ++t) {
        const int c0 = t * 16 + lg * 4;
        const float4 g4 = *(const float4*)(LNG + c0);
        const float4 b4 = *(const float4*)(LNB + c0);
        float r0 = fmaf((o[t][0] - mu) * rs, g4.x, b4.x);
        float r1 = fmaf((o[t][1] - mu) * rs, g4.y, b4.y);
        float r2 = fmaf((o[t][2] - mu) * rs, g4.z, b4.z);
        float r3 = fmaf((o[t][3] - mu) * rs, g4.w, b4.w);
        uint2 pk;
        pk.x = (unsigned)f2bf(r0) | ((unsigned)f2bf(r1) << 16);
        pk.y = (unsigned)f2bf(r2) | ((unsigned)f2bf(r3) << 16);
        if (row < NN) *(uint2*)(hbf + (size_t)row * 128 + c0) = pk;
        *(uint2*)(sArow + c0) = pk;
    }

    // msg G1 swapped
#pragma unroll
    for (int t = 0; t < 8; ++t) acc[t] = (floatx4){0.f, 0.f, 0.f, 0.f};
#pragma unroll
    for (int kb = 0; kb < 4; ++kb) {
        bfrag bv = *(const bfrag*)(sArow + kb * 32 + lg * 8);
#pragma unroll
        for (int t = 0; t < 8; ++t) {
            bfrag av = *(const bfrag*)(W1t + (t * 16 + lr) * 128 + kb * 32 + lg * 8);
            acc[t] = MFMA(av, bv, acc[t]);
        }
    }
#pragma unroll
    for (int t = 0; t < 8; ++t) {
        const float4 b1 = *(const float4*)(B1 + t * 16 + lg * 4);
        float h0 = gelu_t(acc[t][0] + b1.x), h1 = gelu_t(acc[t][1] + b1.y);
        float h2 = gelu_t(acc[t][2] + b1.z), h3 = gelu_t(acc[t][3] + b1.w);
        uint2 p;
        p.x = (unsigned)f2bf(h0) | ((unsigned)f2bf(h1) << 16);
        p.y = (unsigned)f2bf(h2) | ((unsigned)f2bf(h3) << 16);
        *(uint2*)(sArow + t * 16 + lg * 4) = p;
    }
    // msg G2 swapped -> coalesced mbf
#pragma unroll
    for (int t = 0; t < 8; ++t) acc[t] = (floatx4){0.f, 0.f, 0.f, 0.f};
#pragma unroll
    for (int kb = 0; kb < 4; ++kb) {
        bfrag av = *(const bfrag*)(sArow + kb * 32 + lg * 8);
#pragma unroll
        for (int t = 0; t < 8; ++t) {
            bfrag bw = *(const bfrag*)(W2t + (t * 16 + lr) * 128 + kb * 32 + lg * 8);
            acc[t] = MFMA(bw, av, acc[t]);
        }
    }
    if (row < NN) {
        ushort* orow = mbf + (size_t)row * 128;
#pragma unroll
        for (int t = 0; t < 8; ++t) {
            const float4 b2 = *(const float4*)(B2 + t * 16 + lg * 4);
            uint2 p;
            p.x = (unsigned)f2bf(acc[t][0] + b2.x) |
                  ((unsigned)f2bf(acc[t][1] + b2.y) << 16);
            p.y = (unsigned)f2bf(acc[t][2] + b2.z) |
                  ((unsigned)f2bf(acc[t][3] + b2.w) << 16);
            *(uint2*)(orow + t * 16 + lg * 4) = p;
        }
    }
}

// ------- last layer: gate + residual + LN + 3 heads fused ----
__global__ void __launch_bounds__(256)
k_gateheads(const ushort* __restrict__ hbf, const ushort* __restrict__ aggbf,
            const ushort* __restrict__ GWt, const float* __restrict__ GB,
            const float* __restrict__ LNG, const float* __restrict__ LNB,
            const ushort* __restrict__ WHt, float* __restrict__ OUT,
            const float* __restrict__ b1a, const float* __restrict__ b1b,
            const float* __restrict__ b1c,
            const float* __restrict__ w2a, const float* __restrict__ w2b,
            const float* __restrict__ w2c,
            const float* __restrict__ b2a, const float* __restrict__ b2b,
            const float* __restrict__ b2c) {
    __shared__ ushort sA[64 * 136];
    const int tid = threadIdx.x;
    const int w = tid >> 6, lane = tid & 63, lr = lane & 15, lg = lane >> 4;
    const int row = blockIdx.x * 64 + w * 16 + lr;

    bfrag bvv[8];
    uint2 hp[8], ap[8];
#pragma unroll
    for (int kb = 0; kb < 4; ++kb)
        bvv[kb] = *(const bfrag*)(hbf + (size_t)row * 128 + kb * 32 + lg * 8);
#pragma unroll
    for (int kb = 0; kb < 4; ++kb)
        bvv[4 + kb] = *(const bfrag*)(aggbf + (size_t)row * 128 + kb * 32 + lg * 8);
#pragma unroll
    for (int t = 0; t < 8; ++t) {
        hp[t] = *(const uint2*)(hbf + (size_t)row * 128 + t * 16 + lg * 4);
        ap[t] = *(const uint2*)(aggbf + (size_t)row * 128 + t * 16 + lg * 4);
    }

    floatx4 acc[8];
#pragma unroll
    for (int t = 0; t < 8; ++t) acc[t] = (floatx4){0.f, 0.f, 0.f, 0.f};
#pragma unroll
    for (int kb = 0; kb < 8; ++kb) {
#pragma unroll
        for (int t = 0; t < 8; ++t) {
            bfrag av = *(const bfrag*)(GWt + (t * 16 + lr) * 256 + kb * 32 + lg * 8);
            acc[t] = MFMA(av, bvv[kb], acc[t]);
        }
    }
    float o[8][4];
    float s = 0.0f;
#pragma unroll
    for (int t = 0; t < 8; ++t) {
        const int c0 = t * 16 + lg * 4;
        const float4 gb = *(const float4*)(GB + c0);
        float h0 = bf2f((ushort)(hp[t].x & 0xFFFF)), h1 = bf2f((ushort)(hp[t].x >> 16));
        float h2 = bf2f((ushort)(hp[t].y & 0xFFFF)), h3 = bf2f((ushort)(hp[t].y >> 16));
        float a0 = bf2f((ushort)(ap[t].x & 0xFFFF)), a1 = bf2f((ushort)(ap[t].x >> 16));
        float a2 = bf2f((ushort)(ap[t].y & 0xFFFF)), a3 = bf2f((ushort)(ap[t].y >> 16));
        o[t][0] = h0 + sigm(acc[t][0] + gb.x) * a0;
        o[t][1] = h1 + sigm(acc[t][1] + gb.y) * a1;
        o[t][2] = h2 + sigm(acc[t][2] + gb.z) * a2;
        o[t][3] = h3 + sigm(acc[t][3] + gb.w) * a3;
        s += o[t][0] + o[t][1] + o[t][2] + o[t][3];
    }
    s += __shfl_xor(s, 16);
    s += __shfl_xor(s, 32);
    const float mu = s * (1.0f / 128.0f);
    float q = 0.0f;
#pragma unroll
    for (int t = 0; t < 8; ++t)
#pragma unroll
        for (int r = 0; r < 4; ++r) {
            float dx = o[t][r] - mu;
            q = fmaf(dx, dx, q);
        }
    q += __shfl_xor(q, 16);
    q += __shfl_xor(q, 32);
    const float rs = rsqrtf(q * (1.0f / 128.0f) + 1e-5f);

    ushort* sArow = sA + (w * 16 + lr) * 136;
#pragma unroll
    for (int t = 0; t < 8; ++t) {
        const int c0 = t * 16 + lg * 4;
        const float4 g4 = *(const float4*)(LNG + c0);
        const float4 b4 = *(const float4*)(LNB + c0);
        float r0 = fmaf((o[t][0] - mu) * rs, g4.x, b4.x);
        float r1 = fmaf((o[t][1] - mu) * rs, g4.y, b4.y);
        float r2 = fmaf((o[t][2] - mu) * rs, g4.z, b4.z);
        float r3 = fmaf((o[t][3] - mu) * rs, g4.w, b4.w);
        uint2 pk;
        pk.x = (unsigned)f2bf(r0) | ((unsigned)f2bf(r1) << 16);
        pk.y = (unsigned)f2bf(r2) | ((unsigned)f2bf(r3) << 16);
        *(uint2*)(sArow + c0) = pk;
    }

    floatx4 acc2[12];
#pragma unroll
    for (int t = 0; t < 12; ++t) acc2[t] = (floatx4){0.f, 0.f, 0.f, 0.f};
#pragma unroll
    for (int kb = 0; kb < 4; ++kb) {
        bfrag bv = *(const bfrag*)(sArow + kb * 32 + lg * 8);
#pragma unroll
        for (int t = 0; t < 12; ++t) {
            bfrag av = *(const bfrag*)(WHt + (t * 16 + lr) * 128 + kb * 32 + lg * 8);
            acc2[t] = MFMA(av, bv, acc2[t]);
        }
    }
    const float* b1s[3] = {b1a, b1b, b1c};
    const float* w2s[3] = {w2a, w2b, w2c};
    float p[3] = {0.f, 0.f, 0.f};
#pragma unroll
    for (int t = 0; t < 12; ++t) {
        const int head = t >> 2;
        const int c0 = (t & 3) * 16 + lg * 4;
        const float4 b1 = *(const float4*)(b1s[head] + c0);
        const float4 w2 = *(const float4*)(w2s[head] + c0);
        p[head] += gelu_t(acc2[t][0] + b1.x) * w2.x;
        p[head] += gelu_t(acc2[t][1] + b1.y) * w2.y;
        p[head] += gelu_t(acc2[t][2] + b1.z) * w2.z;
        p[head] += gelu_t(acc2[t][3] + b1.w) * w2.w;
    }
#pragma unroll
    for (int hd = 0; hd < 3; ++hd) {
        p[hd] += __shfl_xor(p[hd], 16);
        p[hd] += __shfl_xor(p[hd], 32);
    }
    if (lg == 0 && row < NN) {
        OUT[0 * NN + row] = p[0] + b2a[0];
        OUT[1 * NN + row] = p[1] + b2b[0];
        OUT[2 * NN + row] = p[2] + b2c[0];
    }
}

extern "C" void kernel_launch(void* const* d_in, const int* in_sizes, int n_in,
                              void* d_out, int out_size, void* d_ws, size_t ws_size,
                              hipStream_t stream) {
    const float* x       = (const float*)d_in[0];
    const int*   ei      = (const int*)d_in[1];
    const float* ea      = (const float*)d_in[2];
    const float* enc_w1  = (const float*)d_in[3];
    const float* enc_b1  = (const float*)d_in[4];
    const float* enc_w2  = (const float*)d_in[5];
    const float* enc_b2  = (const float*)d_in[6];
    const float* edge_w1 = (const float*)d_in[7];
    const float* edge_b1 = (const float*)d_in[8];
    const float* edge_w2 = (const float*)d_in[9];
    const float* edge_b2 = (const float*)d_in[10];
    const float* msg_w1  = (const float*)d_in[11];
    const float* msg_b1  = (const float*)d_in[12];
    const float* msg_w2  = (const float*)d_in[13];
    const float* msg_b2  = (const float*)d_in[14];
    const float* gate_w  = (const float*)d_in[15];
    const float* gate_b  = (const float*)d_in[16];
    const float* ln_g    = (const float*)d_in[17];
    const float* ln_b    = (const float*)d_in[18];
    const float* hw[12];
    for (int t = 0; t < 12; ++t) hw[t] = (const float*)d_in[19 + t];

    const size_t NNH = (size_t)NN2 * H;
    ushort* hbf   = (ushort*)d_ws;
    ushort* mbf   = hbf + NNH;
    ushort* aggbf = mbf + NNH;
    ushort* xbf   = aggbf + NNH;                   // NN2*32
    ushort* eapbf = xbf + (size_t)NN2 * 32;        // NE*16 (permuted)
    ushort* wt    = eapbf + (size_t)NE * 16;
    ushort* wt_enc1 = wt;                          // 128*32
    ushort* wt_enc2 = wt_enc1 + 128 * 32;          // 128*128
    ushort* wt_e1   = wt_enc2 + 128 * 128;         // 4*128*32
    ushort* wt_e2   = wt_e1 + 4 * 128 * 32;        // 4*128*128
    ushort* wt_m1   = wt_e2 + 4 * 128 * 128;       // 4*128*128
    ushort* wt_m2   = wt_m1 + 4 * 128 * 128;       // 4*128*128
    ushort* wt_g    = wt_m2 + 4 * 128 * 128;       // 4*128*256
    ushort* wt_h    = wt_g + 4 * 128 * 256;        // 192*128
    int* row_ptr = (int*)(wt_h + 192 * 128 + 64);
    int* perm    = row_ptr + 100352;
    int* nf      = perm + NE;
    int* nl      = nf + 10240;
    int* hist    = nl + 10240;
    int* incl    = hist + 100352;
    int* cursor  = incl + 100352;
    int* bsum    = cursor + 100352;
    uintptr_t ewp_addr = ((uintptr_t)(bsum + 512) + 15) & ~(uintptr_t)15;
    ushort* ewp = (ushort*)ewp_addr;
    const size_t used = ewp_addr - (uintptr_t)d_ws;

    int P = 4;
    size_t rows = NE / 4 + 1024;
    if (ws_size >= used + (size_t)NE * 128 * 2) { P = 1; rows = NE; }
    else if (ws_size >= used + ((size_t)NE / 2 + 1024) * 128 * 2) { P = 2; rows = NE / 2 + 1024; }
    const int PE = NE / P;
    const int NGB = 10000 / P;
    const int ewblk = (int)(rows / 128);

    // ---- sort by dst (CSR + perm) — proven separate-kernel chain ----
    k_init3<<<(NN + 255) / 256, 256, 0, stream>>>(hist, nf, nl);
    hipMemsetAsync(aggbf, 0, NNH * sizeof(ushort), stream);
    k_hist<<<(NE + 255) / 256, 256, 0, stream>>>(ei, hist);
    k_scan1<<<NSB, 256, 0, stream>>>(hist, incl, bsum);
    k_scan2<<<1, 512, 0, stream>>>(bsum);
    k_scan3<<<NSB, 256, 0, stream>>>(hist, incl, bsum, row_ptr, cursor);
    k_scatter<<<(NE + 255) / 256, 256, 0, stream>>>(ei, cursor, perm);
    k_blockrange<<<(NN + 255) / 256, 256, 0, stream>>>(row_ptr, nf, nl);

    // ---- converts: all weights + x in one launch; permuted edge attrs ----
    k_wtall<<<14024, 256, 0, stream>>>(wt, xbf, x, enc_w1, enc_w2, edge_w1, edge_w2,
                                       msg_w1, msg_w2, gate_w, hw[0], hw[4], hw[8]);
    k_cvtperm<<<(NE + 255) / 256, 256, 0, stream>>>(ea, perm, eapbf);

    // ---- network ----
    const int ntiles = NN2 / 64;
    k_encmsg<<<ntiles, 256, 0, stream>>>(xbf, hbf, mbf,
        wt_enc1, enc_b1, wt_enc2, enc_b2,
        wt_m1, msg_b1, wt_m2, msg_b2);

    for (int l = 0; l < NL; ++l) {
        for (int p = 0; p < P; ++p) {
            const int S = p * PE;
            k_ew<<<ewblk, 256, 0, stream>>>(eapbf, ewp, S,
                wt_e1 + (size_t)l * 128 * 32, edge_b1 + l * H,
                wt_e2 + (size_t)l * 128 * 128, edge_b2 + l * H);
            const int nb = (p == P - 1) ? (NGB + 1) : NGB;
            k_gms<<<nb, 256, 0, stream>>>(ei, perm, row_ptr,
                nf + p * NGB, nl + p * NGB, ewp, S, mbf, aggbf);
        }
        if (l < NL - 1) {
            k_gatemlp<<<ntiles, 256, 0, stream>>>(hbf, aggbf,
                wt_g + (size_t)l * 128 * 256, gate_b + l * H,
                ln_g + l * H, ln_b + l * H,
                wt_m1 + (size_t)(l + 1) * 128 * 128, msg_b1 + (l + 1) * H,
                wt_m2 + (size_t)(l + 1) * 128 * 128, msg_b2 + (l + 1) * H, mbf);
        } else {
            k_gateheads<<<ntiles, 256, 0, stream>>>(hbf, aggbf,
                wt_g + (size_t)l * 128 * 256, gate_b + l * H,
                ln_g + l * H, ln_b + l * H,
                wt_h, (float*)d_out,
                hw[1], hw[5], hw[9], hw[2], hw[6], hw[10], hw[3], hw[7], hw[11]);
        }
    }
}